// Round 1
// baseline (329.588 us; speedup 1.0000x reference)
//
#include <hip/hip_runtime.h>

#define B_ 2
#define H_ 16
#define N_ 2048
#define D_ 64
#define NH_ (B_*H_)            // 32 heads
#define ROWS_ (NH_*N_)         // 65536 rows per tensor

typedef _Float16 f16;
typedef _Float16 f16x4 __attribute__((ext_vector_type(4)));
typedef _Float16 f16x8 __attribute__((ext_vector_type(8)));
typedef float f32x4 __attribute__((ext_vector_type(4)));

// ---------------------------------------------------------------------------
// Prep 1: convert q,k f32->f16; bias[head][j] = mask ? -1e30 : -|k_j|^2
// Each wave handles 4 rows of 64 (lane: sub-row = lane>>4, elem4 = lane&15).
// Grid: 2*ROWS_/16 blocks of 256 threads.
// ---------------------------------------------------------------------------
__global__ __launch_bounds__(256) void prep_qk(
    const float* __restrict__ q, const float* __restrict__ k,
    const void* __restrict__ mask,
    f16* __restrict__ qh, f16* __restrict__ kh, float* __restrict__ bias) {
  int tid  = threadIdx.x;
  int wave = tid >> 6, lane = tid & 63;
  int sub  = lane >> 4, e = lane & 15;
  long gr  = (long)blockIdx.x * 4 + wave;   // row-group (4 rows)
  bool isK = gr >= (ROWS_ / 4);
  long rg  = isK ? gr - (ROWS_ / 4) : gr;
  long row = rg * 4 + sub;

  const float* src = (isK ? k : q) + row * D_ + e * 4;
  f32x4 v = *(const f32x4*)src;
  f16x4 hv;
  hv[0] = (f16)v[0]; hv[1] = (f16)v[1]; hv[2] = (f16)v[2]; hv[3] = (f16)v[3];
  f16* dst = (isK ? kh : qh) + row * D_ + e * 4;
  *(f16x4*)dst = hv;

  if (isK) {
    float s = v[0]*v[0] + v[1]*v[1] + v[2]*v[2] + v[3]*v[3];
    s += __shfl_xor(s, 1); s += __shfl_xor(s, 2);
    s += __shfl_xor(s, 4); s += __shfl_xor(s, 8);
    // mask dtype detection: int32 mask has all first-64 words in {0,1};
    // a byte (bool) mask almost surely has some word > 1.
    const unsigned* mw = (const unsigned*)mask;
    unsigned x = mw[lane];
    bool bytes_mode = __any(x > 1u);
    if (e == 0) {
      int b = (int)(row / ((long)H_ * N_));
      int j = (int)(row % N_);
      int mv = bytes_mode ? (int)((const unsigned char*)mask)[b * N_ + j]
                          : ((const int*)mask)[b * N_ + j];
      bias[row] = mv ? -1e30f : -s;
    }
  }
}

// ---------------------------------------------------------------------------
// Prep 2: vt[head][d][n] = (f16) v[head][n][d]   (64x64 tiles via LDS)
// Grid: NH_*(N_/64) = 1024 blocks of 256 threads.
// ---------------------------------------------------------------------------
__global__ __launch_bounds__(256) void prep_vt(
    const float* __restrict__ v, f16* __restrict__ vt) {
  __shared__ f16 T[64][72];
  int t = threadIdx.x;
  int head = blockIdx.x >> 5;
  int n0   = (blockIdx.x & 31) << 6;
  const float* src = v + ((long)head * N_ + n0) * D_;
#pragma unroll
  for (int p = 0; p < 4; ++p) {
    int r  = p * 16 + (t >> 4);   // n within tile
    int d4 = (t & 15);
    f32x4 x = *(const f32x4*)(src + r * D_ + d4 * 4);
    T[d4*4+0][r] = (f16)x[0];
    T[d4*4+1][r] = (f16)x[1];
    T[d4*4+2][r] = (f16)x[2];
    T[d4*4+3][r] = (f16)x[3];
  }
  __syncthreads();
  f16* dst = vt + (long)head * D_ * N_;
#pragma unroll
  for (int p = 0; p < 4; ++p) {
    int d  = p * 16 + (t >> 4);
    int nc = (t & 15) * 4;
    f16x4 y;
    y[0] = T[d][nc]; y[1] = T[d][nc+1]; y[2] = T[d][nc+2]; y[3] = T[d][nc+3];
    *(f16x4*)(dst + (long)d * N_ + n0 + nc) = y;
  }
}

// ---------------------------------------------------------------------------
// Main: flash attention. Block = 4 waves; wave owns 16 q-rows.
// Grid: NH_*(N_/64) = 1024 blocks of 256 threads.
// Score s = 0.25*(q.k) + bias_j   (bias = -|k|^2, masked -> -1e30;
// the -|q|^2 term is constant per row and cancels in softmax).
// ---------------------------------------------------------------------------
__global__ __launch_bounds__(256) void attend_main(
    const f16* __restrict__ qh, const f16* __restrict__ kh,
    const f16* __restrict__ vt, const float* __restrict__ bias,
    float* __restrict__ out) {
  __shared__ f16 P[4][16][72];   // per-wave P transpose buffer (+8 pad)

  int tid  = threadIdx.x;
  int w    = tid >> 6, lane = tid & 63;
  int j    = lane & 15, g = lane >> 4;
  int head = blockIdx.x >> 5;
  int qt   = blockIdx.x & 31;
  int qrow0 = qt * 64 + w * 16;

  // Q A-fragments: row = j (lane%16), k(d) = g*8 + 32*c
  const f16* qbase = qh + ((long)head * N_ + qrow0 + j) * D_;
  f16x8 qf0 = *(const f16x8*)(qbase + g * 8);
  f16x8 qf1 = *(const f16x8*)(qbase + 32 + g * 8);

  f32x4 O0 = {0.f,0.f,0.f,0.f}, O1 = {0.f,0.f,0.f,0.f};
  f32x4 O2 = {0.f,0.f,0.f,0.f}, O3 = {0.f,0.f,0.f,0.f};
  float m[4] = {-1e30f,-1e30f,-1e30f,-1e30f};
  float l[4] = {0.f,0.f,0.f,0.f};

  const f16*  kbase = kh + (long)head * N_ * D_;
  const f16*  vbase = vt + (long)head * D_ * N_;
  const float* bb   = bias + (long)head * N_;

  for (int kv = 0; kv < N_; kv += 64) {
    // ---- QK^T: 4 tiles of 16 keys, 2 MFMAs each ----
    float s[4][4];
#pragma unroll
    for (int jt = 0; jt < 4; ++jt) {
      f32x4 a = {0.f,0.f,0.f,0.f};
      const f16* kr = kbase + (long)(kv + jt * 16 + j) * D_ + g * 8;
      a = __builtin_amdgcn_mfma_f32_16x16x32_f16(qf0, *(const f16x8*)kr,        a, 0, 0, 0);
      a = __builtin_amdgcn_mfma_f32_16x16x32_f16(qf1, *(const f16x8*)(kr + 32), a, 0, 0, 0);
      float bj = bb[kv + jt * 16 + j];
#pragma unroll
      for (int r = 0; r < 4; ++r) s[jt][r] = a[r] * 0.25f + bj;
    }
    // ---- online softmax (rows = g*4+r, cols across 16-lane group) ----
    float tm[4];
#pragma unroll
    for (int r = 0; r < 4; ++r)
      tm[r] = fmaxf(fmaxf(s[0][r], s[1][r]), fmaxf(s[2][r], s[3][r]));
#pragma unroll
    for (int off = 1; off < 16; off <<= 1)
#pragma unroll
      for (int r = 0; r < 4; ++r) tm[r] = fmaxf(tm[r], __shfl_xor(tm[r], off));
    float sc[4];
#pragma unroll
    for (int r = 0; r < 4; ++r) {
      float mn = fmaxf(m[r], tm[r]);
      sc[r] = __expf(m[r] - mn);
      m[r] = mn;
      l[r] *= sc[r];
      O0[r] *= sc[r]; O1[r] *= sc[r]; O2[r] *= sc[r]; O3[r] *= sc[r];
    }
    float rs[4] = {0.f,0.f,0.f,0.f};
#pragma unroll
    for (int jt = 0; jt < 4; ++jt)
#pragma unroll
      for (int r = 0; r < 4; ++r) {
        float p = __expf(s[jt][r] - m[r]);
        s[jt][r] = p;
        rs[r] += p;
      }
#pragma unroll
    for (int off = 1; off < 16; off <<= 1)
#pragma unroll
      for (int r = 0; r < 4; ++r) rs[r] += __shfl_xor(rs[r], off);
#pragma unroll
    for (int r = 0; r < 4; ++r) l[r] += rs[r];

    // ---- P -> LDS (C/D layout) then read back as A-fragments ----
#pragma unroll
    for (int jt = 0; jt < 4; ++jt)
#pragma unroll
      for (int r = 0; r < 4; ++r)
        P[w][g * 4 + r][jt * 16 + j] = (f16)s[jt][r];

    const f16* pr = &P[w][j][0];
    f16x8 pf0 = *(const f16x8*)(pr + g * 8);
    f16x8 pf1 = *(const f16x8*)(pr + 32 + g * 8);

    // ---- PV: O[16q x 64d] += P[16q x 64k] * V[64k x 64d] ----
    const f16* vr = vbase + kv + g * 8;
    O0 = __builtin_amdgcn_mfma_f32_16x16x32_f16(pf0, *(const f16x8*)(vr + (long)(0*16 + j) * N_),      O0, 0, 0, 0);
    O0 = __builtin_amdgcn_mfma_f32_16x16x32_f16(pf1, *(const f16x8*)(vr + (long)(0*16 + j) * N_ + 32), O0, 0, 0, 0);
    O1 = __builtin_amdgcn_mfma_f32_16x16x32_f16(pf0, *(const f16x8*)(vr + (long)(1*16 + j) * N_),      O1, 0, 0, 0);
    O1 = __builtin_amdgcn_mfma_f32_16x16x32_f16(pf1, *(const f16x8*)(vr + (long)(1*16 + j) * N_ + 32), O1, 0, 0, 0);
    O2 = __builtin_amdgcn_mfma_f32_16x16x32_f16(pf0, *(const f16x8*)(vr + (long)(2*16 + j) * N_),      O2, 0, 0, 0);
    O2 = __builtin_amdgcn_mfma_f32_16x16x32_f16(pf1, *(const f16x8*)(vr + (long)(2*16 + j) * N_ + 32), O2, 0, 0, 0);
    O3 = __builtin_amdgcn_mfma_f32_16x16x32_f16(pf0, *(const f16x8*)(vr + (long)(3*16 + j) * N_),      O3, 0, 0, 0);
    O3 = __builtin_amdgcn_mfma_f32_16x16x32_f16(pf1, *(const f16x8*)(vr + (long)(3*16 + j) * N_ + 32), O3, 0, 0, 0);
  }

  // ---- epilogue: out[row][d] = O[row][d] / l[row] ----
  float* ob = out + ((long)head * N_ + qrow0 + g * 4) * D_ + j;
#pragma unroll
  for (int r = 0; r < 4; ++r) {
    float inv = 1.0f / l[r];
    float* o2 = ob + (long)r * D_;
    o2[0]  = O0[r] * inv;
    o2[16] = O1[r] * inv;
    o2[32] = O2[r] * inv;
    o2[48] = O3[r] * inv;
  }
}

extern "C" void kernel_launch(void* const* d_in, const int* in_sizes, int n_in,
                              void* d_out, int out_size, void* d_ws, size_t ws_size,
                              hipStream_t stream) {
  const float* q = (const float*)d_in[0];
  const float* k = (const float*)d_in[1];
  const float* v = (const float*)d_in[2];
  const void* mask = d_in[3];

  char* ws = (char*)d_ws;
  f16*   qh   = (f16*)ws;                       //  8 MiB
  f16*   kh   = (f16*)(ws + (8u  << 20));       //  8 MiB
  f16*   vt   = (f16*)(ws + (16u << 20));       //  8 MiB
  float* bias = (float*)(ws + (24u << 20));     // 256 KiB
  float* out  = (float*)d_out;

  prep_qk<<<dim3(2 * ROWS_ / 16), dim3(256), 0, stream>>>(q, k, mask, qh, kh, bias);
  prep_vt<<<dim3(NH_ * (N_ / 64)), dim3(256), 0, stream>>>(v, vt);
  attend_main<<<dim3(NH_ * (N_ / 64)), dim3(256), 0, stream>>>(qh, kh, vt, bias, out);
}

// Round 3
// 201.994 us; speedup vs baseline: 1.6317x; 1.6317x over previous
//
#include <hip/hip_runtime.h>

#define B_ 2
#define H_ 16
#define N_ 2048
#define D_ 64
#define NH_ (B_*H_)            // 32 heads
#define ROWS_ (NH_*N_)         // 65536 rows per tensor
#define KVB 64
#define NT (N_/KVB)            // 32 kv tiles

typedef _Float16 f16;
typedef _Float16 f16x4 __attribute__((ext_vector_type(4)));
typedef _Float16 f16x8 __attribute__((ext_vector_type(8)));
typedef float f32x4 __attribute__((ext_vector_type(4)));

typedef __attribute__((address_space(1))) const void g_void;
typedef __attribute__((address_space(3))) void l_void;

__device__ __forceinline__ void gl_lds16(const void* g, void* l) {
  __builtin_amdgcn_global_load_lds((g_void*)g, (l_void*)l, 16, 0, 0);
}

// ---------------------------------------------------------------------------
// Prep (merged): blocks [0,8192): q,k f32->f16 + bias; blocks [8192,9216): v^T.
// ---------------------------------------------------------------------------
__global__ __launch_bounds__(256) void prep_all(
    const float* __restrict__ q, const float* __restrict__ k,
    const float* __restrict__ v, const void* __restrict__ mask,
    f16* __restrict__ qh, f16* __restrict__ kh, f16* __restrict__ vt,
    float* __restrict__ bias) {
  __shared__ f16 T[64][72];
  int tid = threadIdx.x;
  if (blockIdx.x < 8192) {
    int wave = tid >> 6, lane = tid & 63;
    int sub = lane >> 4, e = lane & 15;
    long gr = (long)blockIdx.x * 4 + wave;
    bool isK = gr >= (ROWS_ / 4);
    long rg = isK ? gr - (ROWS_ / 4) : gr;
    long row = rg * 4 + sub;

    const float* src = (isK ? k : q) + row * D_ + e * 4;
    f32x4 x = *(const f32x4*)src;
    f16x4 hv;
    hv[0] = (f16)x[0]; hv[1] = (f16)x[1]; hv[2] = (f16)x[2]; hv[3] = (f16)x[3];
    f16* dst = (isK ? kh : qh) + row * D_ + e * 4;
    *(f16x4*)dst = hv;

    if (isK) {
      float s = x[0]*x[0] + x[1]*x[1] + x[2]*x[2] + x[3]*x[3];
      s += __shfl_xor(s, 1); s += __shfl_xor(s, 2);
      s += __shfl_xor(s, 4); s += __shfl_xor(s, 8);
      const unsigned* mw = (const unsigned*)mask;
      unsigned xm = mw[lane];
      bool bytes_mode = __any(xm > 1u);
      if (e == 0) {
        int b = (int)(row / ((long)H_ * N_));
        int jj = (int)(row % N_);
        int mv = bytes_mode ? (int)((const unsigned char*)mask)[b * N_ + jj]
                            : ((const int*)mask)[b * N_ + jj];
        bias[row] = mv ? -1e30f : -s;
      }
    }
  } else {
    int vb = blockIdx.x - 8192;
    int head = vb >> 5;
    int n0 = (vb & 31) << 6;
    const float* src = v + ((long)head * N_ + n0) * D_;
#pragma unroll
    for (int p = 0; p < 4; ++p) {
      int r = p * 16 + (tid >> 4);
      int d4 = (tid & 15);
      f32x4 x = *(const f32x4*)(src + r * D_ + d4 * 4);
      T[d4*4+0][r] = (f16)x[0];
      T[d4*4+1][r] = (f16)x[1];
      T[d4*4+2][r] = (f16)x[2];
      T[d4*4+3][r] = (f16)x[3];
    }
    __syncthreads();
    f16* dst = vt + (long)head * D_ * N_;
#pragma unroll
    for (int p = 0; p < 4; ++p) {
      int d = p * 16 + (tid >> 4);
      int nc = (tid & 15) * 4;
      f16x4 y;
      y[0] = T[d][nc]; y[1] = T[d][nc+1]; y[2] = T[d][nc+2]; y[3] = T[d][nc+3];
      *(f16x4*)(dst + (long)d * N_ + n0 + nc) = y;
    }
  }
}

// ---------------------------------------------------------------------------
// Main: flash attention, 2-phase double-buffered LDS staging.
// Block = 4 waves, 64 q-rows (16/wave). Grid 1024. LDS = 40960 B -> 4 blk/CU.
// K tile [64 kv][64 d] f16, V^T tile [64 d][64 kv] f16, both XOR-swizzled
// (byte ^= ((row&7)<<4)) via pre-swizzled global SOURCE + linear LDS dst.
// ---------------------------------------------------------------------------
__global__ __launch_bounds__(256, 4) void attend_main(
    const f16* __restrict__ qh, const f16* __restrict__ kh,
    const f16* __restrict__ vt, const float* __restrict__ bias,
    float* __restrict__ out) {
  __shared__ f16 Kt[2][4096];    // 16 KiB
  __shared__ f16 Vt[2][4096];    // 16 KiB
  __shared__ f16 Pb[4][1024];    // 8 KiB, per-wave [16 q][64 k] swizzled

  int tid = threadIdx.x;
  int w = tid >> 6, lane = tid & 63;
  int j = lane & 15, g = lane >> 4;

  // XCD-bijective swizzle: 1024 % 8 == 0, consecutive heads stay on one XCD.
  int bid = (blockIdx.x & 7) * 128 + (blockIdx.x >> 3);
  int head = bid >> 5;
  int qt = bid & 31;
  int qrow0 = qt * 64 + w * 16;

  const f16* qbase = qh + ((long)head * N_ + qrow0 + j) * D_;
  f16x8 qf0 = *(const f16x8*)(qbase + g * 8);
  f16x8 qf1 = *(const f16x8*)(qbase + 32 + g * 8);

  const char* kg = (const char*)(kh + (long)head * N_ * D_);  // 128B rows, contiguous
  const char* vg = (const char*)(vt + (long)head * D_ * N_);  // rows stride N_*2 bytes
  const float* bb = bias + (long)head * N_;

  f32x4 O0 = {0.f,0.f,0.f,0.f}, O1 = {0.f,0.f,0.f,0.f};
  f32x4 O2 = {0.f,0.f,0.f,0.f}, O3 = {0.f,0.f,0.f,0.f};
  float m[4] = {-1e30f,-1e30f,-1e30f,-1e30f};
  float l[4] = {0.f,0.f,0.f,0.f};

  auto stage = [&](int buf, int t) {
    int kv = t * KVB;
    if (w < 2) {                      // K tile: 8KB contiguous at kg + kv*128
      const char* src = kg + (size_t)kv * 128;
      char* lb = (char*)&Kt[buf][0];
#pragma unroll
      for (int c = 0; c < 4; ++c) {
        int chunk = w * 4 + c;
        int o = chunk * 1024 + lane * 16;
        int p = o ^ (((o >> 7) & 7) << 4);   // inverse-swizzled source offset
        gl_lds16(src + p, lb + chunk * 1024);
      }
    } else {                          // V^T tile: 64 rows of 128B, stride N_*2
      const char* src = vg + (size_t)kv * 2;
      char* lb = (char*)&Vt[buf][0];
#pragma unroll
      for (int c = 0; c < 4; ++c) {
        int chunk = (w - 2) * 4 + c;
        int o = chunk * 1024 + lane * 16;
        int p = o ^ (((o >> 7) & 7) << 4);
        gl_lds16(src + (size_t)(p >> 7) * (N_ * 2) + (p & 127), lb + chunk * 1024);
      }
    }
  };

  float bnx[4];
#pragma unroll
  for (int jt = 0; jt < 4; ++jt) bnx[jt] = bb[jt * 16 + j];

  stage(0, 0);
  __syncthreads();                   // prologue: tile 0 resident
  int cur = 0;

  for (int t = 0; t < NT; ++t) {
    float bc[4];
#pragma unroll
    for (int jt = 0; jt < 4; ++jt) bc[jt] = bnx[jt];
    if (t + 1 < NT) {
      stage(cur ^ 1, t + 1);         // async prefetch, overlaps with compute
#pragma unroll
      for (int jt = 0; jt < 4; ++jt) bnx[jt] = bb[(t + 1) * KVB + jt * 16 + j];
    }

    const char* Kc = (const char*)&Kt[cur][0];
    const char* Vc = (const char*)&Vt[cur][0];

    // ---- QK^T from LDS ----
    float s[4][4];
#pragma unroll
    for (int jt = 0; jt < 4; ++jt) {
      int r = jt * 16 + j;
      int base = r << 7;
      int sw = (r & 7) << 4;
      f16x8 k0 = *(const f16x8*)(Kc + ((base + g * 16) ^ sw));
      f16x8 k1 = *(const f16x8*)(Kc + ((base + 64 + g * 16) ^ sw));
      f32x4 a = {0.f,0.f,0.f,0.f};
      a = __builtin_amdgcn_mfma_f32_16x16x32_f16(qf0, k0, a, 0, 0, 0);
      a = __builtin_amdgcn_mfma_f32_16x16x32_f16(qf1, k1, a, 0, 0, 0);
#pragma unroll
      for (int r2 = 0; r2 < 4; ++r2) s[jt][r2] = a[r2] * 0.25f + bc[jt];
    }

    // ---- online softmax (rows q = g*4+r, cols k spread over 16 j-lanes) ----
    float tm[4];
#pragma unroll
    for (int r = 0; r < 4; ++r)
      tm[r] = fmaxf(fmaxf(s[0][r], s[1][r]), fmaxf(s[2][r], s[3][r]));
#pragma unroll
    for (int off = 1; off < 16; off <<= 1)
#pragma unroll
      for (int r = 0; r < 4; ++r) tm[r] = fmaxf(tm[r], __shfl_xor(tm[r], off));
#pragma unroll
    for (int r = 0; r < 4; ++r) {
      float mn = fmaxf(m[r], tm[r]);
      float sc = __expf(m[r] - mn);
      m[r] = mn;
      l[r] *= sc;
      O0[r] *= sc; O1[r] *= sc; O2[r] *= sc; O3[r] *= sc;
    }
    float rs[4] = {0.f,0.f,0.f,0.f};
#pragma unroll
    for (int jt = 0; jt < 4; ++jt)
#pragma unroll
      for (int r = 0; r < 4; ++r) {
        float p = __expf(s[jt][r] - m[r]);
        s[jt][r] = p;
        rs[r] += p;
      }
#pragma unroll
    for (int off = 1; off < 16; off <<= 1)
#pragma unroll
      for (int r = 0; r < 4; ++r) rs[r] += __shfl_xor(rs[r], off);
#pragma unroll
    for (int r = 0; r < 4; ++r) l[r] += rs[r];

    // ---- P -> LDS (swizzled) then read back as A-fragments ----
    char* Pw = (char*)&Pb[w][0];
#pragma unroll
    for (int jt = 0; jt < 4; ++jt)
#pragma unroll
      for (int r = 0; r < 4; ++r) {
        int row = g * 4 + r;
        int off = ((row << 7) + (jt * 16 + j) * 2) ^ ((row & 7) << 4);
        *(f16*)(Pw + off) = (f16)s[jt][r];
      }
    {
      int swp = (j & 7) << 4;
      f16x8 pf0 = *(const f16x8*)(Pw + (((j << 7) + g * 16) ^ swp));
      f16x8 pf1 = *(const f16x8*)(Pw + (((j << 7) + 64 + g * 16) ^ swp));

      // ---- PV from LDS V^T tile ----
#pragma unroll
      for (int dt = 0; dt < 4; ++dt) {
        int row = dt * 16 + j;
        int base = row << 7;
        int sw = (row & 7) << 4;
        f16x8 v0 = *(const f16x8*)(Vc + ((base + g * 16) ^ sw));
        f16x8 v1 = *(const f16x8*)(Vc + ((base + 64 + g * 16) ^ sw));
        f32x4* Od = (dt == 0) ? &O0 : (dt == 1) ? &O1 : (dt == 2) ? &O2 : &O3;
        *Od = __builtin_amdgcn_mfma_f32_16x16x32_f16(pf0, v0, *Od, 0, 0, 0);
        *Od = __builtin_amdgcn_mfma_f32_16x16x32_f16(pf1, v1, *Od, 0, 0, 0);
      }
    }

    __syncthreads();                 // drains prefetch (vmcnt 0) + barrier
    cur ^= 1;
  }

  // ---- epilogue ----
  float* ob = out + ((long)head * N_ + qrow0 + g * 4) * D_ + j;
#pragma unroll
  for (int r = 0; r < 4; ++r) {
    float inv = 1.0f / l[r];
    float* o2 = ob + (long)r * D_;
    o2[0]  = O0[r] * inv;
    o2[16] = O1[r] * inv;
    o2[32] = O2[r] * inv;
    o2[48] = O3[r] * inv;
  }
}

extern "C" void kernel_launch(void* const* d_in, const int* in_sizes, int n_in,
                              void* d_out, int out_size, void* d_ws, size_t ws_size,
                              hipStream_t stream) {
  const float* q = (const float*)d_in[0];
  const float* k = (const float*)d_in[1];
  const float* v = (const float*)d_in[2];
  const void* mask = d_in[3];

  char* ws = (char*)d_ws;
  f16*   qh   = (f16*)ws;                       //  8 MiB
  f16*   kh   = (f16*)(ws + (8u  << 20));       //  8 MiB
  f16*   vt   = (f16*)(ws + (16u << 20));       //  8 MiB
  float* bias = (float*)(ws + (24u << 20));     // 256 KiB
  float* out  = (float*)d_out;

  prep_all<<<dim3(8192 + 1024), dim3(256), 0, stream>>>(q, k, v, mask, qh, kh, vt, bias);
  attend_main<<<dim3(NH_ * (N_ / 64)), dim3(256), 0, stream>>>(qh, kh, vt, bias, out);
}

// Round 4
// 161.769 us; speedup vs baseline: 2.0374x; 1.2487x over previous
//
#include <hip/hip_runtime.h>

#define B_ 2
#define H_ 16
#define N_ 2048
#define D_ 64
#define NH_ (B_*H_)            // 32 heads
#define ROWS_ (NH_*N_)         // 65536 rows per tensor
#define KVB 64
#define NT (N_/KVB)            // 32 kv tiles
#define LOG2E 1.4426950408889634f
#define QSCALE (0.25f * LOG2E)

typedef _Float16 f16;
typedef _Float16 f16x4 __attribute__((ext_vector_type(4)));
typedef _Float16 f16x8 __attribute__((ext_vector_type(8)));
typedef float f32x4 __attribute__((ext_vector_type(4)));

typedef __attribute__((address_space(1))) const void g_void;
typedef __attribute__((address_space(3))) void l_void;

__device__ __forceinline__ void gl_lds16(const void* g, void* l) {
  __builtin_amdgcn_global_load_lds((g_void*)g, (l_void*)l, 16, 0, 0);
}

// ---------------------------------------------------------------------------
// Prep: blocks [0,1024): V^T via in-register 4x4 transpose (no LDS).
//       blocks [1024,2048): q,k f32->f16 (+bias) grid-stride, 8 lanes/row.
// qh = f16(0.25*log2e * q)  (scale+log2 domain folded)
// bias = masked ? -1e30 : -|k|^2 * log2e
// ---------------------------------------------------------------------------
__global__ __launch_bounds__(256) void prep_all(
    const float* __restrict__ q, const float* __restrict__ k,
    const float* __restrict__ v, const void* __restrict__ mask,
    f16* __restrict__ qh, f16* __restrict__ kh, f16* __restrict__ vt,
    float* __restrict__ bias) {
  int tid = threadIdx.x;
  if (blockIdx.x < 1024) {
    // ---- V^T tile: 64 n x 64 d, lane owns a 4x4 micro-tile ----
    int head = blockIdx.x >> 5;
    int n0 = (blockIdx.x & 31) << 6;
    int e = tid & 15, gq = tid >> 4;        // n-sub = e*4, d0 = gq*4
    const float* src = v + ((long)head * N_ + n0 + e * 4) * D_ + gq * 4;
    f32x4 r0 = *(const f32x4*)(src);
    f32x4 r1 = *(const f32x4*)(src + D_);
    f32x4 r2 = *(const f32x4*)(src + 2 * D_);
    f32x4 r3 = *(const f32x4*)(src + 3 * D_);
    f16* dst = vt + (long)head * D_ * N_ + n0 + e * 4;
#pragma unroll
    for (int c = 0; c < 4; ++c) {
      f16x4 y;
      y[0] = (f16)r0[c]; y[1] = (f16)r1[c]; y[2] = (f16)r2[c]; y[3] = (f16)r3[c];
      *(f16x4*)(dst + (long)(gq * 4 + c) * N_) = y;
    }
  } else {
    // ---- q/k convert: wave = 8 rows, lane: r8 = lane>>3, e = lane&7 ----
    int wid = (blockIdx.x - 1024) * 4 + (tid >> 6);   // 0..4095
    int lane = tid & 63;
    int r8 = lane >> 3, e = lane & 7;
    const unsigned* mw = (const unsigned*)mask;
    bool bytes_mode = __any(mw[lane] > 1u);
#pragma unroll
    for (int trip = 0; trip < 4; ++trip) {
      long grow = ((long)(trip * 4096 + wid)) * 8 + r8;  // 0..131071
      bool isK = grow >= ROWS_;
      long row = isK ? grow - ROWS_ : grow;
      const float* s = (isK ? k : q) + row * D_ + e * 8;
      f32x4 x0 = *(const f32x4*)s;
      f32x4 x1 = *(const f32x4*)(s + 4);
      float scl = isK ? 1.0f : QSCALE;
      f16x8 hv;
#pragma unroll
      for (int c = 0; c < 4; ++c) { hv[c] = (f16)(x0[c] * scl); hv[4 + c] = (f16)(x1[c] * scl); }
      *(f16x8*)((isK ? kh : qh) + row * D_ + e * 8) = hv;
      if (isK) {
        float sq = x0[0]*x0[0] + x0[1]*x0[1] + x0[2]*x0[2] + x0[3]*x0[3]
                 + x1[0]*x1[0] + x1[1]*x1[1] + x1[2]*x1[2] + x1[3]*x1[3];
        sq += __shfl_xor(sq, 1); sq += __shfl_xor(sq, 2); sq += __shfl_xor(sq, 4);
        if (e == 0) {
          int b = (int)(row >> 15);             // row / (H_*N_)
          int n = (int)(row & (N_ - 1));
          int mv = bytes_mode ? (int)((const unsigned char*)mask)[b * N_ + n]
                              : ((const int*)mask)[b * N_ + n];
          bias[row] = mv ? -1e30f : -sq * LOG2E;
        }
      }
    }
  }
}

// ---------------------------------------------------------------------------
// Main: flash attention, swapped-operand QK^T (A=K, B=Q) so each lane holds
// 16 scores of ONE q-row (q = lane&15) -> in-register softmax (2 shfl steps).
// Bias pre-loaded into the MFMA accumulator (no per-score VALU pass).
// Block = 4 waves x 16 q-rows. 2-phase double-buffered LDS staging via
// global_load_lds w=16, source-side XOR swizzle. LDS 40KB -> 4 blk/CU.
// ---------------------------------------------------------------------------
__global__ __launch_bounds__(256, 4) void attend_main(
    const f16* __restrict__ qh, const f16* __restrict__ kh,
    const f16* __restrict__ vt, const float* __restrict__ bias,
    float* __restrict__ out) {
  __shared__ f16 Kt[2][4096];    // 16 KiB
  __shared__ f16 Vt[2][4096];    // 16 KiB
  __shared__ f16 Pb[4][1024];    // 8 KiB, per-wave [16 q][64 k] swizzled

  int tid = threadIdx.x;
  int w = tid >> 6, lane = tid & 63;
  int j = lane & 15, g = lane >> 4;

  // XCD-bijective swizzle (1024 % 8 == 0)
  int bid = (blockIdx.x & 7) * 128 + (blockIdx.x >> 3);
  int head = bid >> 5;
  int qt = bid & 31;
  int qrow0 = qt * 64 + w * 16;

  const f16* qbase = qh + ((long)head * N_ + qrow0 + j) * D_;
  f16x8 qf0 = *(const f16x8*)(qbase + g * 8);
  f16x8 qf1 = *(const f16x8*)(qbase + 32 + g * 8);

  const char* kg = (const char*)(kh + (long)head * N_ * D_);
  const char* vg = (const char*)(vt + (long)head * D_ * N_);
  const float* bb = bias + (long)head * N_ + g * 4;   // pre-offset by g*4

  f32x4 O0 = {0.f,0.f,0.f,0.f}, O1 = {0.f,0.f,0.f,0.f};
  f32x4 O2 = {0.f,0.f,0.f,0.f}, O3 = {0.f,0.f,0.f,0.f};
  float m = -1e30f, l = 0.f;    // per-lane state for q-row j

  auto stage = [&](int buf, int t) {
    int kv = t * KVB;
    if (w < 2) {                      // K tile: 8KB contiguous
      const char* src = kg + (size_t)kv * 128;
      char* lb = (char*)&Kt[buf][0];
#pragma unroll
      for (int c = 0; c < 4; ++c) {
        int chunk = w * 4 + c;
        int o = chunk * 1024 + lane * 16;
        int p = o ^ (((o >> 7) & 7) << 4);   // inverse-swizzled source offset
        gl_lds16(src + p, lb + chunk * 1024);
      }
    } else {                          // V^T tile: 64 rows of 128B, stride N_*2
      const char* src = vg + (size_t)kv * 2;
      char* lb = (char*)&Vt[buf][0];
#pragma unroll
      for (int c = 0; c < 4; ++c) {
        int chunk = (w - 2) * 4 + c;
        int o = chunk * 1024 + lane * 16;
        int p = o ^ (((o >> 7) & 7) << 4);
        gl_lds16(src + (size_t)(p >> 7) * (N_ * 2) + (p & 127), lb + chunk * 1024);
      }
    }
  };

  f32x4 bnx[4];
#pragma unroll
  for (int jt = 0; jt < 4; ++jt) bnx[jt] = *(const f32x4*)(bb + jt * 16);

  stage(0, 0);
  __syncthreads();
  int cur = 0;

  for (int t = 0; t < NT; ++t) {
    f32x4 sA[4];                      // sA[jt][r] = score[k=jt*16+g*4+r][q=j]
#pragma unroll
    for (int jt = 0; jt < 4; ++jt) sA[jt] = bnx[jt];   // bias as acc-init
    if (t + 1 < NT) {
      stage(cur ^ 1, t + 1);          // async prefetch
#pragma unroll
      for (int jt = 0; jt < 4; ++jt)
        bnx[jt] = *(const f32x4*)(bb + (t + 1) * KVB + jt * 16);
    }

    const char* Kc = (const char*)&Kt[cur][0];
    const char* Vc = (const char*)&Vt[cur][0];

    // ---- QK^T (swapped: A=K, B=Q) ----
    __builtin_amdgcn_s_setprio(1);
#pragma unroll
    for (int jt = 0; jt < 4; ++jt) {
      int r = jt * 16 + j;
      int base = r << 7;
      int sw = (r & 7) << 4;
      f16x8 k0 = *(const f16x8*)(Kc + ((base + g * 16) ^ sw));
      f16x8 k1 = *(const f16x8*)(Kc + ((base + 64 + g * 16) ^ sw));
      sA[jt] = __builtin_amdgcn_mfma_f32_16x16x32_f16(k0, qf0, sA[jt], 0, 0, 0);
      sA[jt] = __builtin_amdgcn_mfma_f32_16x16x32_f16(k1, qf1, sA[jt], 0, 0, 0);
    }
    __builtin_amdgcn_s_setprio(0);

    // ---- in-register online softmax (one q-row per lane) ----
    f32x4 mx0, mx1;
#pragma unroll
    for (int r = 0; r < 4; ++r) { mx0[r] = fmaxf(sA[0][r], sA[1][r]); mx1[r] = fmaxf(sA[2][r], sA[3][r]); }
    float tm = -1e30f;
#pragma unroll
    for (int r = 0; r < 4; ++r) tm = fmaxf(tm, fmaxf(mx0[r], mx1[r]));
    tm = fmaxf(tm, __shfl_xor(tm, 16));
    tm = fmaxf(tm, __shfl_xor(tm, 32));
    float mn = fmaxf(m, tm);
    float sc = __builtin_amdgcn_exp2f(m - mn);
    m = mn;

    float rsum = 0.f;
#pragma unroll
    for (int jt = 0; jt < 4; ++jt)
#pragma unroll
      for (int r = 0; r < 4; ++r) {
        float p = __builtin_amdgcn_exp2f(sA[jt][r] - mn);
        sA[jt][r] = p;
        rsum += p;
      }
    rsum += __shfl_xor(rsum, 16);
    rsum += __shfl_xor(rsum, 32);
    l = l * sc + rsum;

    // rescale O: need scale of q-row g*4+r
#pragma unroll
    for (int r = 0; r < 4; ++r) {
      float scr = __shfl(sc, g * 4 + r);
      O0[r] *= scr; O1[r] *= scr; O2[r] *= scr; O3[r] *= scr;
    }

    // ---- P -> LDS (k contiguous per lane: one b64 write per jt) ----
    char* Pw = (char*)&Pb[w][0];
#pragma unroll
    for (int jt = 0; jt < 4; ++jt) {
      f16x4 pk;
      pk[0] = (f16)sA[jt][0]; pk[1] = (f16)sA[jt][1];
      pk[2] = (f16)sA[jt][2]; pk[3] = (f16)sA[jt][3];
      int off = ((j << 7) + jt * 32 + g * 8) ^ ((j & 7) << 4);
      *(f16x4*)(Pw + off) = pk;
    }
    int swp = (j & 7) << 4;
    f16x8 pf0 = *(const f16x8*)(Pw + (((j << 7) + g * 16) ^ swp));
    f16x8 pf1 = *(const f16x8*)(Pw + (((j << 7) + 64 + g * 16) ^ swp));

    // ---- PV ----
    __builtin_amdgcn_s_setprio(1);
#pragma unroll
    for (int dt = 0; dt < 4; ++dt) {
      int row = dt * 16 + j;
      int base = row << 7;
      int sw = (row & 7) << 4;
      f16x8 v0 = *(const f16x8*)(Vc + ((base + g * 16) ^ sw));
      f16x8 v1 = *(const f16x8*)(Vc + ((base + 64 + g * 16) ^ sw));
      f32x4* Od = (dt == 0) ? &O0 : (dt == 1) ? &O1 : (dt == 2) ? &O2 : &O3;
      *Od = __builtin_amdgcn_mfma_f32_16x16x32_f16(pf0, v0, *Od, 0, 0, 0);
      *Od = __builtin_amdgcn_mfma_f32_16x16x32_f16(pf1, v1, *Od, 0, 0, 0);
    }
    __builtin_amdgcn_s_setprio(0);

    __syncthreads();
    cur ^= 1;
  }

  // ---- epilogue: out[q][d] = O / l[q] ----
  float* ob = out + ((long)head * N_ + qrow0 + g * 4) * D_ + j;
#pragma unroll
  for (int r = 0; r < 4; ++r) {
    float inv = 1.0f / __shfl(l, g * 4 + r);
    float* o2 = ob + (long)r * D_;
    o2[0]  = O0[r] * inv;
    o2[16] = O1[r] * inv;
    o2[32] = O2[r] * inv;
    o2[48] = O3[r] * inv;
  }
}

extern "C" void kernel_launch(void* const* d_in, const int* in_sizes, int n_in,
                              void* d_out, int out_size, void* d_ws, size_t ws_size,
                              hipStream_t stream) {
  const float* q = (const float*)d_in[0];
  const float* k = (const float*)d_in[1];
  const float* v = (const float*)d_in[2];
  const void* mask = d_in[3];

  char* ws = (char*)d_ws;
  f16*   qh   = (f16*)ws;                       //  8 MiB
  f16*   kh   = (f16*)(ws + (8u  << 20));       //  8 MiB
  f16*   vt   = (f16*)(ws + (16u << 20));       //  8 MiB
  float* bias = (float*)(ws + (24u << 20));     // 256 KiB
  float* out  = (float*)d_out;

  prep_all<<<dim3(2048), dim3(256), 0, stream>>>(q, k, v, mask, qh, kh, vt, bias);
  attend_main<<<dim3(NH_ * (N_ / 64)), dim3(256), 0, stream>>>(qh, kh, vt, bias, out);
}

// Round 5
// 155.034 us; speedup vs baseline: 2.1259x; 1.0434x over previous
//
#include <hip/hip_runtime.h>

#define B_ 2
#define H_ 16
#define N_ 2048
#define D_ 64
#define NH_ (B_*H_)            // 32 heads
#define ROWS_ (NH_*N_)         // 65536 rows per tensor
#define KVB 64
#define NT (N_/KVB)            // 32 kv tiles
#define LOG2E 1.4426950408889634f
#define QSCALE (0.25f * LOG2E)

typedef _Float16 f16;
typedef _Float16 f16x4 __attribute__((ext_vector_type(4)));
typedef _Float16 f16x8 __attribute__((ext_vector_type(8)));
typedef float f32x4 __attribute__((ext_vector_type(4)));

typedef __attribute__((address_space(1))) const void g_void;
typedef __attribute__((address_space(3))) void l_void;

__device__ __forceinline__ void gl_lds16(const void* g, void* l) {
  __builtin_amdgcn_global_load_lds((g_void*)g, (l_void*)l, 16, 0, 0);
}

// ---------------------------------------------------------------------------
// Prep: blocks [0,1024): V^T via in-register 4x4 transpose (no LDS).
//       blocks [1024,2048): q,k f32->f16 (+bias) grid-stride, 8 lanes/row.
// qh = f16(0.25*log2e * q); bias = masked ? -1e30 : -|k|^2 * log2e
// ---------------------------------------------------------------------------
__global__ __launch_bounds__(256) void prep_all(
    const float* __restrict__ q, const float* __restrict__ k,
    const float* __restrict__ v, const void* __restrict__ mask,
    f16* __restrict__ qh, f16* __restrict__ kh, f16* __restrict__ vt,
    float* __restrict__ bias) {
  int tid = threadIdx.x;
  if (blockIdx.x < 1024) {
    int head = blockIdx.x >> 5;
    int n0 = (blockIdx.x & 31) << 6;
    int e = tid & 15, gq = tid >> 4;
    const float* src = v + ((long)head * N_ + n0 + e * 4) * D_ + gq * 4;
    f32x4 r0 = *(const f32x4*)(src);
    f32x4 r1 = *(const f32x4*)(src + D_);
    f32x4 r2 = *(const f32x4*)(src + 2 * D_);
    f32x4 r3 = *(const f32x4*)(src + 3 * D_);
    f16* dst = vt + (long)head * D_ * N_ + n0 + e * 4;
#pragma unroll
    for (int c = 0; c < 4; ++c) {
      f16x4 y;
      y[0] = (f16)r0[c]; y[1] = (f16)r1[c]; y[2] = (f16)r2[c]; y[3] = (f16)r3[c];
      *(f16x4*)(dst + (long)(gq * 4 + c) * N_) = y;
    }
  } else {
    int wid = (blockIdx.x - 1024) * 4 + (tid >> 6);
    int lane = tid & 63;
    int r8 = lane >> 3, e = lane & 7;
    const unsigned* mw = (const unsigned*)mask;
    bool bytes_mode = __any(mw[lane] > 1u);
#pragma unroll
    for (int trip = 0; trip < 4; ++trip) {
      long grow = ((long)(trip * 4096 + wid)) * 8 + r8;
      bool isK = grow >= ROWS_;
      long row = isK ? grow - ROWS_ : grow;
      const float* s = (isK ? k : q) + row * D_ + e * 8;
      f32x4 x0 = *(const f32x4*)s;
      f32x4 x1 = *(const f32x4*)(s + 4);
      float scl = isK ? 1.0f : QSCALE;
      f16x8 hv;
#pragma unroll
      for (int c = 0; c < 4; ++c) { hv[c] = (f16)(x0[c] * scl); hv[4 + c] = (f16)(x1[c] * scl); }
      *(f16x8*)((isK ? kh : qh) + row * D_ + e * 8) = hv;
      if (isK) {
        float sq = x0[0]*x0[0] + x0[1]*x0[1] + x0[2]*x0[2] + x0[3]*x0[3]
                 + x1[0]*x1[0] + x1[1]*x1[1] + x1[2]*x1[2] + x1[3]*x1[3];
        sq += __shfl_xor(sq, 1); sq += __shfl_xor(sq, 2); sq += __shfl_xor(sq, 4);
        if (e == 0) {
          int b = (int)(row >> 15);
          int n = (int)(row & (N_ - 1));
          int mv = bytes_mode ? (int)((const unsigned char*)mask)[b * N_ + n]
                              : ((const int*)mask)[b * N_ + n];
          bias[row] = mv ? -1e30f : -sq * LOG2E;
        }
      }
    }
  }
}

// ---------------------------------------------------------------------------
// Main: flash attention, swapped-operand QK^T, in-register softmax,
// defer-max (THR=8, exp2 domain), per-block KV-tile stagger, hoisted offsets.
// Block = 4 waves x 16 q-rows. LDS 40KB -> 4 blk/CU.
// ---------------------------------------------------------------------------
__global__ __launch_bounds__(256, 4) void attend_main(
    const f16* __restrict__ qh, const f16* __restrict__ kh,
    const f16* __restrict__ vt, const float* __restrict__ bias,
    float* __restrict__ out) {
  __shared__ f16 Kt[2][4096];
  __shared__ f16 Vt[2][4096];
  __shared__ f16 Pb[4][1024];

  int tid = threadIdx.x;
  int w = tid >> 6, lane = tid & 63;
  int j = lane & 15, g = lane >> 4;

  int bid = (blockIdx.x & 7) * 128 + (blockIdx.x >> 3);
  int head = bid >> 5;
  int qt = bid & 31;
  int qrow0 = qt * 64 + w * 16;
  int off = ((bid >> 5) & 3) * 8;          // co-resident blocks differ in bit 5

  const f16* qbase = qh + ((long)head * N_ + qrow0 + j) * D_;
  f16x8 qf0 = *(const f16x8*)(qbase + g * 8);
  f16x8 qf1 = *(const f16x8*)(qbase + 32 + g * 8);

  const char* kg = (const char*)(kh + (long)head * N_ * D_);
  const char* vg = (const char*)(vt + (long)head * D_ * N_);
  const float* bb = bias + (long)head * N_ + g * 4;

  // loop-invariant LDS byte offsets (K and V share the same formula)
  int ko0[4], ko1[4];
#pragma unroll
  for (int x = 0; x < 4; ++x) {
    int rk = x * 16 + j;
    int swk = (rk & 7) << 4;
    ko0[x] = ((rk << 7) + g * 16) ^ swk;
    ko1[x] = ((rk << 7) + 64 + g * 16) ^ swk;
  }
  int pswz = (j & 7) << 4;
  int pw0 = ((j << 7) + g * 8) ^ pswz;      // + jt*32 per write
  int pr0 = ((j << 7) + g * 16) ^ pswz;
  int pr1 = ((j << 7) + 64 + g * 16) ^ pswz;

  f32x4 O0 = {0.f,0.f,0.f,0.f}, O1 = {0.f,0.f,0.f,0.f};
  f32x4 O2 = {0.f,0.f,0.f,0.f}, O3 = {0.f,0.f,0.f,0.f};
  float m = -1e30f, l = 0.f;

  auto stage = [&](int buf, int t) {
    int kv = t * KVB;
    if (w < 2) {
      const char* src = kg + (size_t)kv * 128;
      char* lb = (char*)&Kt[buf][0];
#pragma unroll
      for (int c = 0; c < 4; ++c) {
        int chunk = w * 4 + c;
        int o = chunk * 1024 + lane * 16;
        int p = o ^ (((o >> 7) & 7) << 4);
        gl_lds16(src + p, lb + chunk * 1024);
      }
    } else {
      const char* src = vg + (size_t)kv * 2;
      char* lb = (char*)&Vt[buf][0];
#pragma unroll
      for (int c = 0; c < 4; ++c) {
        int chunk = (w - 2) * 4 + c;
        int o = chunk * 1024 + lane * 16;
        int p = o ^ (((o >> 7) & 7) << 4);
        gl_lds16(src + (size_t)(p >> 7) * (N_ * 2) + (p & 127), lb + chunk * 1024);
      }
    }
  };

  f32x4 bnx[4];
#pragma unroll
  for (int jt = 0; jt < 4; ++jt) bnx[jt] = *(const f32x4*)(bb + off * KVB + jt * 16);

  stage(0, off);
  __syncthreads();
  int cur = 0;

  for (int t = 0; t < NT; ++t) {
    int tt = (t + off) & (NT - 1);
    f32x4 sA[4];
#pragma unroll
    for (int jt = 0; jt < 4; ++jt) sA[jt] = bnx[jt];
    if (t + 1 < NT) {
      int tn = (tt + 1) & (NT - 1);
      stage(cur ^ 1, tn);
#pragma unroll
      for (int jt = 0; jt < 4; ++jt)
        bnx[jt] = *(const f32x4*)(bb + tn * KVB + jt * 16);
    }

    const char* Kc = (const char*)&Kt[cur][0];
    const char* Vc = (const char*)&Vt[cur][0];

    // ---- QK^T (A=K, B=Q) ----
    __builtin_amdgcn_s_setprio(1);
#pragma unroll
    for (int jt = 0; jt < 4; ++jt) {
      f16x8 k0 = *(const f16x8*)(Kc + ko0[jt]);
      f16x8 k1 = *(const f16x8*)(Kc + ko1[jt]);
      sA[jt] = __builtin_amdgcn_mfma_f32_16x16x32_f16(k0, qf0, sA[jt], 0, 0, 0);
      sA[jt] = __builtin_amdgcn_mfma_f32_16x16x32_f16(k1, qf1, sA[jt], 0, 0, 0);
    }
    __builtin_amdgcn_s_setprio(0);

    // ---- in-register online softmax with defer-max (THR=8, exp2 domain) ----
    f32x4 mx0, mx1;
#pragma unroll
    for (int r = 0; r < 4; ++r) { mx0[r] = fmaxf(sA[0][r], sA[1][r]); mx1[r] = fmaxf(sA[2][r], sA[3][r]); }
    float tm = -1e30f;
#pragma unroll
    for (int r = 0; r < 4; ++r) tm = fmaxf(tm, fmaxf(mx0[r], mx1[r]));
    tm = fmaxf(tm, __shfl_xor(tm, 16));
    tm = fmaxf(tm, __shfl_xor(tm, 32));

    bool fastok = (tm - m <= 8.0f) && (m > -1e29f);
    if (!__all(fastok)) {
      float mn = fmaxf(m, tm);
      float sc = __builtin_amdgcn_exp2f(m - mn);
      m = mn;
      l *= sc;
#pragma unroll
      for (int r = 0; r < 4; ++r) {
        float scr = __shfl(sc, g * 4 + r);
        O0[r] *= scr; O1[r] *= scr; O2[r] *= scr; O3[r] *= scr;
      }
    }

    float rsum = 0.f;
#pragma unroll
    for (int jt = 0; jt < 4; ++jt)
#pragma unroll
      for (int r = 0; r < 4; ++r) {
        float p = __builtin_amdgcn_exp2f(sA[jt][r] - m);
        sA[jt][r] = p;
        rsum += p;
      }
    rsum += __shfl_xor(rsum, 16);
    rsum += __shfl_xor(rsum, 32);
    l += rsum;

    // ---- P -> LDS (b64 writes) then A-fragments ----
    char* Pw = (char*)&Pb[w][0];
#pragma unroll
    for (int jt = 0; jt < 4; ++jt) {
      f16x4 pk;
      pk[0] = (f16)sA[jt][0]; pk[1] = (f16)sA[jt][1];
      pk[2] = (f16)sA[jt][2]; pk[3] = (f16)sA[jt][3];
      *(f16x4*)(Pw + (pw0 ^ (jt * 32))) = pk;   // jt*32 < 128, XOR==add here
    }
    f16x8 pf0 = *(const f16x8*)(Pw + pr0);
    f16x8 pf1 = *(const f16x8*)(Pw + pr1);

    // ---- PV ----
    __builtin_amdgcn_s_setprio(1);
#pragma unroll
    for (int dt = 0; dt < 4; ++dt) {
      f16x8 v0 = *(const f16x8*)(Vc + ko0[dt]);
      f16x8 v1 = *(const f16x8*)(Vc + ko1[dt]);
      f32x4* Od = (dt == 0) ? &O0 : (dt == 1) ? &O1 : (dt == 2) ? &O2 : &O3;
      *Od = __builtin_amdgcn_mfma_f32_16x16x32_f16(pf0, v0, *Od, 0, 0, 0);
      *Od = __builtin_amdgcn_mfma_f32_16x16x32_f16(pf1, v1, *Od, 0, 0, 0);
    }
    __builtin_amdgcn_s_setprio(0);

    __syncthreads();
    cur ^= 1;
  }

  // ---- epilogue ----
  float* ob = out + ((long)head * N_ + qrow0 + g * 4) * D_ + j;
#pragma unroll
  for (int r = 0; r < 4; ++r) {
    float inv = 1.0f / __shfl(l, g * 4 + r);
    float* o2 = ob + (long)r * D_;
    o2[0]  = O0[r] * inv;
    o2[16] = O1[r] * inv;
    o2[32] = O2[r] * inv;
    o2[48] = O3[r] * inv;
  }
}

extern "C" void kernel_launch(void* const* d_in, const int* in_sizes, int n_in,
                              void* d_out, int out_size, void* d_ws, size_t ws_size,
                              hipStream_t stream) {
  const float* q = (const float*)d_in[0];
  const float* k = (const float*)d_in[1];
  const float* v = (const float*)d_in[2];
  const void* mask = d_in[3];

  char* ws = (char*)d_ws;
  f16*   qh   = (f16*)ws;
  f16*   kh   = (f16*)(ws + (8u  << 20));
  f16*   vt   = (f16*)(ws + (16u << 20));
  float* bias = (float*)(ws + (24u << 20));
  float* out  = (float*)d_out;

  prep_all<<<dim3(2048), dim3(256), 0, stream>>>(q, k, v, mask, qh, kh, vt, bias);
  attend_main<<<dim3(NH_ * (N_ / 64)), dim3(256), 0, stream>>>(qh, kh, vt, bias, out);
}